// Round 1
// baseline (141.668 us; speedup 1.0000x reference)
//
#include <hip/hip_runtime.h>
#include <hip/hip_fp16.h>
#include <cstdint>

typedef _Float16 half8_t __attribute__((ext_vector_type(8)));
typedef float f32x4 __attribute__((ext_vector_type(4)));

#define D_ 1024
#define B_ 4
#define N_ 2048
#define M_ (B_*N_)   // 8192 rows
#define NC_ 3072     // fused q|k|v output cols

// ---------------- workspace layout (bytes, all 256-aligned) ----------------
#define OFF_WCAT  0u            // 3072*1024*2  = 6291456
#define OFF_BCAT  6291456u      // 3072*4       = 12288
#define OFF_XB    6303744u      // 8192*1024*2  = 16777216
#define OFF_Q     23080960u
#define OFF_K     39858176u
#define OFF_V     56635392u
#define OFF_ZP    73412608u     // 8192*32*4    = 1048576
#define OFF_DEXP  74461184u     // 8192*4
#define OFF_SV    74493952u     // 4*16*1024*4  = 262144
#define OFF_INVD  74756096u     // 8192*4
#define OFF_CD    74788864u     // 8192*4

// ---------------- async global->LDS, 16B per lane ----------------
__device__ __forceinline__ void gload_lds16(const void* g, void* l) {
  __builtin_amdgcn_global_load_lds(
      (const __attribute__((address_space(1))) unsigned int*)(uintptr_t)g,
      (__attribute__((address_space(3))) unsigned int*)(uintptr_t)l, 16, 0, 0);
}

// stage a 128x64 fp16 tile (row stride 1024 elems) into LDS, XOR-swizzled
// (swizzle applied by pre-swizzling the GLOBAL source; LDS dest stays linear)
__device__ __forceinline__ void stage128x64(const __half* rowbase, char* lds, int tid) {
#pragma unroll
  for (int inst = 0; inst < 4; ++inst) {
    int L  = inst * 4096 + tid * 16;      // linear LDS byte
    int r  = L >> 7;                      // tile row 0..127
    int cb = L & 127;                     // byte within row
    int cbs = cb ^ ((r & 7) << 4);        // inverse swizzle on source
    gload_lds16((const char*)rowbase + (size_t)r * (D_ * 2) + cbs, lds + L);
  }
}

// read one 16B MFMA fragment from swizzled LDS tile
__device__ __forceinline__ half8_t ldsfrag(const char* lds, int row, int cbyte) {
  int b = (row << 7) + (cbyte ^ ((row & 7) << 4));
  return *reinterpret_cast<const half8_t*>(lds + b);
}

// 128x128 output tile over K=1024, bt layout (both operands [row][k] fp16)
__device__ __forceinline__ void gemm128_core(const __half* Arow0, const __half* Brow0,
                                             char* As, char* Bs, f32x4 acc[4][4]) {
  const int tid  = threadIdx.x;
  const int lane = tid & 63;
  const int wave = tid >> 6;
  const int wm = wave >> 1, wn = wave & 1;
  for (int kt = 0; kt < 16; ++kt) {
    if (kt) __syncthreads();
    stage128x64(Arow0 + kt * 64, As, tid);
    stage128x64(Brow0 + kt * 64, Bs, tid);
    asm volatile("s_waitcnt vmcnt(0)" ::: "memory");
    __syncthreads();
#pragma unroll
    for (int kk = 0; kk < 2; ++kk) {
      const int cbyte = kk * 64 + (lane >> 4) * 16;
      half8_t a[4], b[4];
#pragma unroll
      for (int mf = 0; mf < 4; ++mf) a[mf] = ldsfrag(As, wm * 64 + mf * 16 + (lane & 15), cbyte);
#pragma unroll
      for (int nf = 0; nf < 4; ++nf) b[nf] = ldsfrag(Bs, wn * 64 + nf * 16 + (lane & 15), cbyte);
#pragma unroll
      for (int mf = 0; mf < 4; ++mf)
#pragma unroll
        for (int nf = 0; nf < 4; ++nf)
          acc[mf][nf] = __builtin_amdgcn_mfma_f32_16x16x32_f16(a[mf], b[nf], acc[mf][nf], 0, 0, 0);
    }
  }
}

// ---------------- K1: fp32->fp16 convert + zero partials ----------------
__global__ __launch_bounds__(256) void k_prep(
    const float* __restrict__ x, const float* __restrict__ wq, const float* __restrict__ wk,
    const float* __restrict__ wv, const float* __restrict__ bq, const float* __restrict__ bk,
    const float* __restrict__ bv, __half* __restrict__ xb, __half* __restrict__ wcat,
    float* __restrict__ bcat, float* __restrict__ Zpart) {
  const int NX4 = (M_ * D_) / 4;        // 2097152
  const int NW4 = (D_ * D_) / 4;        // 262144
  const int TOT = NX4 + 3 * NW4;
  int tid0 = blockIdx.x * 256 + threadIdx.x;
  int stride = gridDim.x * 256;
  for (int i = tid0; i < TOT; i += stride) {
    float4 f; __half* dst;
    if (i < NX4) {
      f = ((const float4*)x)[i];
      dst = xb + 4 * (size_t)i;
    } else {
      int j = i - NX4; int w = j / NW4; int o = j - w * NW4;
      const float* src = (w == 0) ? wq : (w == 1) ? wk : wv;
      f = ((const float4*)src)[o];
      dst = wcat + (size_t)w * (D_ * D_) + 4 * (size_t)o;
    }
    __half h0 = __float2half(f.x), h1 = __float2half(f.y),
           h2 = __float2half(f.z), h3 = __float2half(f.w);
    ushort4 u = { __half_as_ushort(h0), __half_as_ushort(h1),
                  __half_as_ushort(h2), __half_as_ushort(h3) };
    *((ushort4*)dst) = u;
  }
  if (tid0 < NC_)
    bcat[tid0] = (tid0 < 1024) ? bq[tid0] : (tid0 < 2048) ? bk[tid0 - 1024] : bv[tid0 - 2048];
  for (int i = tid0; i < M_ * 32; i += stride) Zpart[i] = 0.f;
}

// ---------------- K2: fused QKV GEMM  y = xb @ wcat^T + bcat ----------------
__global__ __launch_bounds__(256) void k_qkv(
    const __half* __restrict__ xb, const __half* __restrict__ wcat,
    const float* __restrict__ bcat,
    __half* __restrict__ q, __half* __restrict__ kx, __half* __restrict__ v) {
  __shared__ __align__(16) char smem[32768];
  char* As = smem; char* Bs = smem + 16384;
  int bid = blockIdx.x;
  int bm = bid / 24, bn = bid % 24;
  f32x4 acc[4][4];
#pragma unroll
  for (int i = 0; i < 4; ++i)
#pragma unroll
    for (int j = 0; j < 4; ++j) acc[i][j] = f32x4{0.f, 0.f, 0.f, 0.f};
  gemm128_core(xb + (size_t)bm * 128 * D_, wcat + (size_t)bn * 128 * D_, As, Bs, acc);

  const int lane = threadIdx.x & 63;
  const int wave = threadIdx.x >> 6;
  const int wm = wave >> 1, wn = wave & 1;
  int sel = bn >> 3;                       // 0=q 1=k 2=v (BN=128 divides 1024)
  __half* outp = (sel == 0) ? q : (sel == 1) ? kx : v;
#pragma unroll
  for (int nf = 0; nf < 4; ++nf) {
    int nloc = wn * 64 + nf * 16 + (lane & 15);
    float bias = bcat[bn * 128 + nloc];
    int ncol = (bn & 7) * 128 + nloc;
#pragma unroll
    for (int mf = 0; mf < 4; ++mf) {
#pragma unroll
      for (int r = 0; r < 4; ++r) {
        int m = bm * 128 + wm * 64 + mf * 16 + (lane >> 4) * 4 + r;
        outp[(size_t)m * D_ + ncol] = __float2half(acc[mf][nf][r] + bias);
      }
    }
  }
}

// ---------------- K3: upper-triangle QK^T row stats ----------------
// per 128x128 tile: Zpart[row][tj*2+wn] = sum_{j>=i in tile} exp(s/32); dexp on diag
__global__ __launch_bounds__(256) void k_stats(
    const __half* __restrict__ q, const __half* __restrict__ kx,
    float* __restrict__ Zpart, float* __restrict__ dexp) {
  __shared__ __align__(16) char smem[32768];
  int bid = blockIdx.x;
  int b = bid / 136;
  int r = bid % 136;
  int ti = 0;
  while (r >= 16 - ti) { r -= 16 - ti; ++ti; }
  int tj = ti + r;

  f32x4 acc[4][4];
#pragma unroll
  for (int i = 0; i < 4; ++i)
#pragma unroll
    for (int j = 0; j < 4; ++j) acc[i][j] = f32x4{0.f, 0.f, 0.f, 0.f};
  const size_t base = (size_t)b * N_ * D_;
  gemm128_core(q + base + (size_t)ti * 128 * D_, kx + base + (size_t)tj * 128 * D_,
               smem, smem + 16384, acc);

  const int lane = threadIdx.x & 63;
  const int wave = threadIdx.x >> 6;
  const int wm = wave >> 1, wn = wave & 1;
  const bool offd = (tj > ti);
  const float scale = 0.03125f;            // 1/sqrt(1024)
  int zrow0 = b * N_ + ti * 128;
#pragma unroll
  for (int mf = 0; mf < 4; ++mf) {
#pragma unroll
    for (int rg = 0; rg < 4; ++rg) {
      int il = wm * 64 + mf * 16 + (lane >> 4) * 4 + rg;   // row in tile
      float ssum = 0.f;
#pragma unroll
      for (int nf = 0; nf < 4; ++nf) {
        int jl = wn * 64 + nf * 16 + (lane & 15);           // col in tile
        float e = __expf(acc[mf][nf][rg] * scale);
        bool keep = offd || (jl >= il);
        if (!offd && jl == il) dexp[zrow0 + il] = e;
        ssum += keep ? e : 0.f;
      }
      ssum += __shfl_xor(ssum, 1);
      ssum += __shfl_xor(ssum, 2);
      ssum += __shfl_xor(ssum, 4);
      ssum += __shfl_xor(ssum, 8);
      if ((lane & 15) == 0)
        Zpart[(size_t)(zrow0 + il) * 32 + tj * 2 + wn] = ssum;
    }
  }
}

// ---------------- K4a: v chunk sums + per-row 1/D, dexp/D ----------------
__global__ __launch_bounds__(256) void k_mid(
    const __half* __restrict__ v, const float* __restrict__ Zpart,
    const float* __restrict__ dexp, float* __restrict__ Sv,
    float* __restrict__ invD, float* __restrict__ cdiag) {
  int tid = blockIdx.x * 256 + threadIdx.x;     // 65536 threads
  int b = tid >> 14, c = (tid >> 10) & 15, d = tid & 1023;
  const __half* vp = v + ((size_t)(b * N_ + c * 128)) * D_ + d;
  float s = 0.f;
#pragma unroll 8
  for (int r2 = 0; r2 < 128; ++r2) s += __half2float(vp[(size_t)r2 * D_]);
  Sv[tid] = s;
  if (tid < M_) {
    float z = 0.f;
#pragma unroll
    for (int t = 0; t < 32; ++t) z += Zpart[(size_t)tid * 32 + t];
    float Dd = (float)(tid & (N_ - 1)) + z;     // i + sum_{j>=i} exp(s_ij)
    float iv = 1.f / Dd;
    invD[tid] = iv;
    cdiag[tid] = dexp[tid] * iv;
  }
}

// ---------------- K4b: prefix-scan blend -> output ----------------
__global__ __launch_bounds__(256) void k_out(
    const __half* __restrict__ v, const float* __restrict__ Sv,
    const float* __restrict__ invD, const float* __restrict__ cdiag,
    float* __restrict__ out) {
  int tid = blockIdx.x * 256 + threadIdx.x;
  int b = tid >> 14, c = (tid >> 10) & 15, d = tid & 1023;
  float run = 0.f;
  for (int cc = 0; cc < c; ++cc) run += Sv[((b << 4) + cc) * 1024 + d];
  const __half* vp = v + ((size_t)(b * N_ + c * 128)) * D_ + d;
  float* op = out + ((size_t)(b * N_ + c * 128)) * D_ + d;
  int zi0 = b * N_ + c * 128;
#pragma unroll 4
  for (int r2 = 0; r2 < 128; ++r2) {
    float vi = __half2float(vp[(size_t)r2 * D_]);
    op[(size_t)r2 * D_] = run * invD[zi0 + r2] + cdiag[zi0 + r2] * vi;
    run += vi;
  }
}

extern "C" void kernel_launch(void* const* d_in, const int* in_sizes, int n_in,
                              void* d_out, int out_size, void* d_ws, size_t ws_size,
                              hipStream_t stream) {
  const float* x  = (const float*)d_in[0];
  const float* wq = (const float*)d_in[1];
  const float* bq = (const float*)d_in[2];
  const float* wk = (const float*)d_in[3];
  const float* bk = (const float*)d_in[4];
  const float* wv = (const float*)d_in[5];
  const float* bv = (const float*)d_in[6];
  float* out = (float*)d_out;
  char* ws = (char*)d_ws;

  __half* wcat = (__half*)(ws + OFF_WCAT);
  float*  bcat = (float*)(ws + OFF_BCAT);
  __half* xb   = (__half*)(ws + OFF_XB);
  __half* q    = (__half*)(ws + OFF_Q);
  __half* k    = (__half*)(ws + OFF_K);
  __half* v    = (__half*)(ws + OFF_V);
  float* Zpart = (float*)(ws + OFF_ZP);
  float* dexp  = (float*)(ws + OFF_DEXP);
  float* Sv    = (float*)(ws + OFF_SV);
  float* invD  = (float*)(ws + OFF_INVD);
  float* cdiag = (float*)(ws + OFF_CD);

  k_prep<<<dim3(2048), dim3(256), 0, stream>>>(x, wq, wk, wv, bq, bk, bv, xb, wcat, bcat, Zpart);
  k_qkv<<<dim3(64 * 24), dim3(256), 0, stream>>>(xb, wcat, bcat, q, k, v);
  k_stats<<<dim3(4 * 136), dim3(256), 0, stream>>>(q, k, Zpart, dexp);
  k_mid<<<dim3(256), dim3(256), 0, stream>>>(v, Zpart, dexp, Sv, invD, cdiag);
  k_out<<<dim3(256), dim3(256), 0, stream>>>(v, Sv, invD, cdiag, out);
}